// Round 1
// baseline (18004.326 us; speedup 1.0000x reference)
//
#include <hip/hip_runtime.h>
#include <stdint.h>

#define T_STEPS 8192
#define DIN     2048
#define NH      256      // hidden size H
#define G4      1024     // 4*H
#define OUTW    2560     // DIN + 2*H

// ---------------------------------------------------------------- helpers
__device__ __forceinline__ float sigf(float x) {
    return 1.0f / (1.0f + __expf(-x));
}

__device__ __forceinline__ int dot4(int a, int b, int c) {
#if __has_builtin(__builtin_amdgcn_sdot4)
    return __builtin_amdgcn_sdot4(a, b, c, false);
#else
    int r = c;
#pragma unroll
    for (int i = 0; i < 4; ++i) {
        int ai = (a << (24 - 8 * i)) >> 24;
        int bi = (b << (24 - 8 * i)) >> 24;
        r += ai * bi;
    }
    return r;
#endif
}

// ---------------------------------------------------------------- quantize U
// Each block handles one U matrix (H x 4H row-major). Per-column int8 quant.
// Output layout: word[w*G4 + j] packs rows 4w..4w+3 of column j.
// sc[j] = combined scale = (maxabs/127) * (1/127): z = acc * sc.
__global__ void quant_u_kernel(const float* __restrict__ U0, const float* __restrict__ U1,
                               const float* __restrict__ U2, const float* __restrict__ U3,
                               uint32_t* __restrict__ uq, float* __restrict__ sc) {
    const float* U = (blockIdx.x == 0) ? U0 : (blockIdx.x == 1) ? U1
                   : (blockIdx.x == 2) ? U2 : U3;
    uint32_t* uqo = uq + (size_t)blockIdx.x * (NH / 4) * G4;
    float* sco = sc + (size_t)blockIdx.x * G4;

    int j = threadIdx.x;  // 0..1023, one column per thread
    float ma = 0.f;
    for (int k = 0; k < NH; ++k) ma = fmaxf(ma, fabsf(U[(size_t)k * G4 + j]));
    float inv = (ma > 0.f) ? 127.f / ma : 0.f;
    sco[j] = ma * (1.0f / (127.f * 127.f));
    for (int w = 0; w < NH / 4; ++w) {
        uint32_t word = 0;
#pragma unroll
        for (int b = 0; b < 4; ++b) {
            float v = U[(size_t)(4 * w + b) * G4 + j];
            int q = __float2int_rn(v * inv);
            q = max(-127, min(127, q));
            word |= ((uint32_t)(q & 0xff)) << (8 * b);
        }
        uqo[(size_t)w * G4 + j] = word;
    }
}

// ---------------------------------------------------------------- copy x into both output slabs
__global__ void copy_x_kernel(const float4* __restrict__ x4, float* __restrict__ out) {
    const int total = 2 * T_STEPS * (DIN / 4);  // 8388608
    for (int i = blockIdx.x * blockDim.x + threadIdx.x; i < total;
         i += gridDim.x * blockDim.x) {
        int o   = i >> 22;             // T_STEPS*(DIN/4) = 2^22
        int rem = i & ((1 << 22) - 1);
        int t   = rem >> 9;            // DIN/4 = 512 = 2^9
        int c4  = rem & 511;
        float4 v = x4[(size_t)t * 512 + c4];
        *(float4*)(out + (size_t)o * T_STEPS * OUTW + (size_t)t * OUTW + (size_t)c4 * 4) = v;
    }
}

// ---------------------------------------------------------------- f32 tiled GEMM: C = A @ B + bias
// A: M x K row-major (lda), B: K x 1024 row-major, C: M x 1024.
// Block: 256 threads, 64x64 tile, each thread 4x4.
__global__ __launch_bounds__(256) void gemm_zx_kernel(
    const float* __restrict__ A, int lda,
    const float* __restrict__ B, const float* __restrict__ bias,
    float* __restrict__ C, int K) {
    __shared__ float As[64][17];
    __shared__ float Bs[16][68];
    int tid = threadIdx.x;
    int bm = blockIdx.y * 64, bn = blockIdx.x * 64;
    int trow = tid >> 4, tcol = tid & 15;
    int ar = tid >> 2, ac = (tid & 3) * 4;
    int br = tid >> 4, bc = (tid & 15) * 4;
    float acc[4][4] = {};

    for (int k0 = 0; k0 < K; k0 += 16) {
        float4 av = *(const float4*)(A + (size_t)(bm + ar) * lda + k0 + ac);
        float4 bv = *(const float4*)(B + (size_t)(k0 + br) * G4 + bn + bc);
        As[ar][ac + 0] = av.x; As[ar][ac + 1] = av.y;
        As[ar][ac + 2] = av.z; As[ar][ac + 3] = av.w;
        Bs[br][bc + 0] = bv.x; Bs[br][bc + 1] = bv.y;
        Bs[br][bc + 2] = bv.z; Bs[br][bc + 3] = bv.w;
        __syncthreads();
#pragma unroll
        for (int kk = 0; kk < 16; ++kk) {
            float af[4], bf[4];
#pragma unroll
            for (int i = 0; i < 4; ++i) af[i] = As[trow * 4 + i][kk];
#pragma unroll
            for (int i = 0; i < 4; ++i) bf[i] = Bs[kk][tcol * 4 + i];
#pragma unroll
            for (int i = 0; i < 4; ++i)
#pragma unroll
                for (int j = 0; j < 4; ++j)
                    acc[i][j] = fmaf(af[i], bf[j], acc[i][j]);
        }
        __syncthreads();
    }
#pragma unroll
    for (int i = 0; i < 4; ++i) {
        float4 v;
        v.x = acc[i][0] + bias[bn + tcol * 4 + 0];
        v.y = acc[i][1] + bias[bn + tcol * 4 + 1];
        v.z = acc[i][2] + bias[bn + tcol * 4 + 2];
        v.w = acc[i][3] + bias[bn + tcol * 4 + 3];
        *(float4*)(C + (size_t)(bm + trow * 4 + i) * G4 + bn + tcol * 4) = v;
    }
}

// ---------------------------------------------------------------- sequential LSTM scan
// grid = 2 blocks (dir 0 = forward, dir 1 = backward), 512 threads each.
// Thread j owns output columns j (gates i/f) and j+512 (gates g/o),
// with its int8 U columns resident in 128 VGPRs.
// h is exchanged through LDS as packed int8 (scale 127).
__global__ __launch_bounds__(512) void lstm_scan_kernel(
    const float* __restrict__ Zxf, const float* __restrict__ Zxb,
    const uint32_t* __restrict__ Uqf, const uint32_t* __restrict__ Uqb,
    const float* __restrict__ scf, const float* __restrict__ scb,
    float* __restrict__ outbase) {
    __shared__ float z_lds[G4];
    __shared__ int4 hq_lds4[16];  // 64 words = 256 int8 h values

    const int dir = blockIdx.x;
    const float* Zx = dir ? Zxb : Zxf;
    const uint32_t* Uq = dir ? Uqb : Uqf;
    const float* sc = dir ? scb : scf;

    const int j = threadIdx.x;   // 0..511
    const int j2 = j + 512;

    // U columns into registers (int8 packed, 64+64 words)
    uint32_t uqa[64], uqb_[64];
#pragma unroll
    for (int w = 0; w < 64; ++w) {
        uqa[w]  = Uq[(size_t)w * G4 + j];
        uqb_[w] = Uq[(size_t)w * G4 + j2];
    }
    const float sca = sc[j];
    const float scb2 = sc[j2];

    if (j < 16) hq_lds4[j] = make_int4(0, 0, 0, 0);
    float c = 0.f;

    const int step = dir ? -1 : 1;
    int t = dir ? (T_STEPS - 1) : 0;
    float zxa = Zx[(size_t)t * G4 + j];
    float zxb = Zx[(size_t)t * G4 + j2];
    float* outp = outbase + 2048 + dir * NH;
    __syncthreads();

    for (int s = 0; s < T_STEPS; ++s) {
        const int tn = (s + 1 < T_STEPS) ? t + step : t;
        // prefetch next step's zx row (latency hidden under this step's compute)
        const float nzxa = Zx[(size_t)tn * G4 + j];
        const float nzxb = Zx[(size_t)tn * G4 + j2];

        int acca = 0, accb = 0;
#pragma unroll
        for (int w4 = 0; w4 < 16; ++w4) {
            int4 hw = hq_lds4[w4];  // broadcast read
            acca = dot4(uqa[4 * w4 + 0], hw.x, acca);
            acca = dot4(uqa[4 * w4 + 1], hw.y, acca);
            acca = dot4(uqa[4 * w4 + 2], hw.z, acca);
            acca = dot4(uqa[4 * w4 + 3], hw.w, acca);
            accb = dot4(uqb_[4 * w4 + 0], hw.x, accb);
            accb = dot4(uqb_[4 * w4 + 1], hw.y, accb);
            accb = dot4(uqb_[4 * w4 + 2], hw.z, accb);
            accb = dot4(uqb_[4 * w4 + 3], hw.w, accb);
        }
        z_lds[j]  = zxa + (float)acca * sca;
        z_lds[j2] = zxb + (float)accb * scb2;
        __syncthreads();

        if (j < NH) {
            float zi = z_lds[j];
            float zf = z_lds[j + NH];
            float zg = z_lds[j + 2 * NH];
            float zo = z_lds[j + 3 * NH];
            c = sigf(zf) * c + sigf(zi) * sigf(zg);
            float h = sigf(zo) * sigf(c);
            outp[(size_t)t * OUTW + j] = h;
            int q = __float2int_rn(h * 127.f);
            q = max(0, min(127, q));
            ((uint8_t*)hq_lds4)[j] = (uint8_t)q;
        }
        __syncthreads();

        zxa = nzxa; zxb = nzxb;
        t = tn;
    }
}

// ---------------------------------------------------------------- launch
extern "C" void kernel_launch(void* const* d_in, const int* in_sizes, int n_in,
                              void* d_out, int out_size, void* d_ws, size_t ws_size,
                              hipStream_t stream) {
    const float* x   = (const float*)d_in[0];
    const float* W1f = (const float*)d_in[1];
    const float* U1f = (const float*)d_in[2];
    const float* b1f = (const float*)d_in[3];
    const float* W1b = (const float*)d_in[4];
    const float* U1b = (const float*)d_in[5];
    const float* b1b = (const float*)d_in[6];
    const float* W2f = (const float*)d_in[7];
    const float* U2f = (const float*)d_in[8];
    const float* b2f = (const float*)d_in[9];
    const float* W2b = (const float*)d_in[10];
    const float* U2b = (const float*)d_in[11];
    const float* b2b = (const float*)d_in[12];

    float* out  = (float*)d_out;
    float* out1 = out + (size_t)T_STEPS * OUTW;

    // workspace layout
    float* Zxf = (float*)d_ws;
    float* Zxb = Zxf + (size_t)T_STEPS * G4;
    uint32_t* uq = (uint32_t*)(Zxb + (size_t)T_STEPS * G4);  // 4 * 64*1024 words
    float* scq = (float*)(uq + (size_t)4 * 64 * G4);          // 4 * 1024 floats

    // 1) quantize the four U matrices
    quant_u_kernel<<<4, 1024, 0, stream>>>(U1f, U1b, U2f, U2b, uq, scq);

    // 2) copy x into both output slabs
    copy_x_kernel<<<2048, 256, 0, stream>>>((const float4*)x, out);

    dim3 gg(16, 128);
    // 3) layer-1 input projections
    gemm_zx_kernel<<<gg, 256, 0, stream>>>(x, DIN, W1f, b1f, Zxf, DIN);
    gemm_zx_kernel<<<gg, 256, 0, stream>>>(x, DIN, W1b, b1b, Zxb, DIN);

    // 4) layer-1 scans (write M1 into out slab 0, cols 2048..2559)
    lstm_scan_kernel<<<2, 512, 0, stream>>>(Zxf, Zxb,
                                            uq + (size_t)0 * 64 * G4, uq + (size_t)1 * 64 * G4,
                                            scq + 0 * G4, scq + 1 * G4, out);

    // 5) layer-2 input projections (A = M1, read from out slab 0)
    gemm_zx_kernel<<<gg, 256, 0, stream>>>(out + 2048, OUTW, W2f, b2f, Zxf, 512);
    gemm_zx_kernel<<<gg, 256, 0, stream>>>(out + 2048, OUTW, W2b, b2b, Zxb, 512);

    // 6) layer-2 scans (write M2 into out slab 1)
    lstm_scan_kernel<<<2, 512, 0, stream>>>(Zxf, Zxb,
                                            uq + (size_t)2 * 64 * G4, uq + (size_t)3 * 64 * G4,
                                            scq + 2 * G4, scq + 3 * G4, out1);
}

// Round 2
// 16993.263 us; speedup vs baseline: 1.0595x; 1.0595x over previous
//
#include <hip/hip_runtime.h>
#include <stdint.h>

#define T_STEPS 8192
#define DIN     2048
#define NH      256      // hidden size H
#define G4      1024     // 4*H
#define OUTW    2560     // DIN + 2*H

// ---------------------------------------------------------------- helpers
__device__ __forceinline__ float sigf(float x) {
    return 1.0f / (1.0f + __expf(-x));
}

__device__ __forceinline__ int dot4(int a, int b, int c) {
#if __has_builtin(__builtin_amdgcn_sdot4)
    return __builtin_amdgcn_sdot4(a, b, c, false);
#else
    int r = c;
#pragma unroll
    for (int i = 0; i < 4; ++i) {
        int ai = (a << (24 - 8 * i)) >> 24;
        int bi = (b << (24 - 8 * i)) >> 24;
        r += ai * bi;
    }
    return r;
#endif
}

// ---------------------------------------------------------------- quantize U
// Each block handles one U matrix (H x 4H row-major). Per-column int8 quant.
// Output layout: word[w*G4 + j] packs rows 4w..4w+3 of column j.
// sc[j] = combined scale = (maxabs/127) * (1/127): z = acc * sc.
__global__ void quant_u_kernel(const float* __restrict__ U0, const float* __restrict__ U1,
                               const float* __restrict__ U2, const float* __restrict__ U3,
                               uint32_t* __restrict__ uq, float* __restrict__ sc) {
    const float* U = (blockIdx.x == 0) ? U0 : (blockIdx.x == 1) ? U1
                   : (blockIdx.x == 2) ? U2 : U3;
    uint32_t* uqo = uq + (size_t)blockIdx.x * (NH / 4) * G4;
    float* sco = sc + (size_t)blockIdx.x * G4;

    int j = threadIdx.x;  // 0..1023, one column per thread
    float ma = 0.f;
    for (int k = 0; k < NH; ++k) ma = fmaxf(ma, fabsf(U[(size_t)k * G4 + j]));
    float inv = (ma > 0.f) ? 127.f / ma : 0.f;
    sco[j] = ma * (1.0f / (127.f * 127.f));
    for (int w = 0; w < NH / 4; ++w) {
        uint32_t word = 0;
#pragma unroll
        for (int b = 0; b < 4; ++b) {
            float v = U[(size_t)(4 * w + b) * G4 + j];
            int q = __float2int_rn(v * inv);
            q = max(-127, min(127, q));
            word |= ((uint32_t)(q & 0xff)) << (8 * b);
        }
        uqo[(size_t)w * G4 + j] = word;
    }
}

// ---------------------------------------------------------------- copy x into both output slabs
__global__ void copy_x_kernel(const float4* __restrict__ x4, float* __restrict__ out) {
    const int total = 2 * T_STEPS * (DIN / 4);  // 8388608
    for (int i = blockIdx.x * blockDim.x + threadIdx.x; i < total;
         i += gridDim.x * blockDim.x) {
        int o   = i >> 22;             // T_STEPS*(DIN/4) = 2^22
        int rem = i & ((1 << 22) - 1);
        int t   = rem >> 9;            // DIN/4 = 512 = 2^9
        int c4  = rem & 511;
        float4 v = x4[(size_t)t * 512 + c4];
        *(float4*)(out + (size_t)o * T_STEPS * OUTW + (size_t)t * OUTW + (size_t)c4 * 4) = v;
    }
}

// ---------------------------------------------------------------- f32 tiled GEMM: C = A @ B + bias
// A: M x K row-major (lda), B: K x 1024 row-major, C: M x 1024.
// Block: 256 threads, 64x64 tile, each thread 4x4.
__global__ __launch_bounds__(256) void gemm_zx_kernel(
    const float* __restrict__ A, int lda,
    const float* __restrict__ B, const float* __restrict__ bias,
    float* __restrict__ C, int K) {
    __shared__ float As[64][17];
    __shared__ float Bs[16][68];
    int tid = threadIdx.x;
    int bm = blockIdx.y * 64, bn = blockIdx.x * 64;
    int trow = tid >> 4, tcol = tid & 15;
    int ar = tid >> 2, ac = (tid & 3) * 4;
    int br = tid >> 4, bc = (tid & 15) * 4;
    float acc[4][4] = {};

    for (int k0 = 0; k0 < K; k0 += 16) {
        float4 av = *(const float4*)(A + (size_t)(bm + ar) * lda + k0 + ac);
        float4 bv = *(const float4*)(B + (size_t)(k0 + br) * G4 + bn + bc);
        As[ar][ac + 0] = av.x; As[ar][ac + 1] = av.y;
        As[ar][ac + 2] = av.z; As[ar][ac + 3] = av.w;
        Bs[br][bc + 0] = bv.x; Bs[br][bc + 1] = bv.y;
        Bs[br][bc + 2] = bv.z; Bs[br][bc + 3] = bv.w;
        __syncthreads();
#pragma unroll
        for (int kk = 0; kk < 16; ++kk) {
            float af[4], bf[4];
#pragma unroll
            for (int i = 0; i < 4; ++i) af[i] = As[trow * 4 + i][kk];
#pragma unroll
            for (int i = 0; i < 4; ++i) bf[i] = Bs[kk][tcol * 4 + i];
#pragma unroll
            for (int i = 0; i < 4; ++i)
#pragma unroll
                for (int j = 0; j < 4; ++j)
                    acc[i][j] = fmaf(af[i], bf[j], acc[i][j]);
        }
        __syncthreads();
    }
#pragma unroll
    for (int i = 0; i < 4; ++i) {
        float4 v;
        v.x = acc[i][0] + bias[bn + tcol * 4 + 0];
        v.y = acc[i][1] + bias[bn + tcol * 4 + 1];
        v.z = acc[i][2] + bias[bn + tcol * 4 + 2];
        v.w = acc[i][3] + bias[bn + tcol * 4 + 3];
        *(float4*)(C + (size_t)(bm + trow * 4 + i) * G4 + bn + tcol * 4) = v;
    }
}

// ---------------------------------------------------------------- sequential LSTM scan
// grid = 2 blocks (dir 0 = forward, dir 1 = backward), 1024 threads each.
// Thread j owns output column j with its 64 int8-packed U words pinned in VGPRs.
// h is exchanged through LDS as packed int8 (scale 127).
__global__ __launch_bounds__(1024, 4) void lstm_scan_kernel(
    const float* __restrict__ Zxf, const float* __restrict__ Zxb,
    const uint32_t* __restrict__ Uqf, const uint32_t* __restrict__ Uqb,
    const float* __restrict__ scf, const float* __restrict__ scb,
    float* __restrict__ outbase) {
    __shared__ float z_lds[G4];
    __shared__ int4 hq_lds4[16];  // 64 words = 256 int8 h values

    const int dir = blockIdx.x;
    const float* Zx = dir ? Zxb : Zxf;
    const uint32_t* Uq = dir ? Uqb : Uqf;
    const float* sc = dir ? scb : scf;

    const int j = threadIdx.x;   // 0..1023, one gate-column per thread

    // U column j into 64 VGPRs (int8 packed)
    int u[64];
#pragma unroll
    for (int w = 0; w < 64; ++w) u[w] = (int)Uq[(size_t)w * G4 + j];
    // Pin in registers: mark as asm-modified so the loads cannot be
    // rematerialized inside the time loop.
#pragma unroll
    for (int w = 0; w < 64; w += 4)
        asm volatile("" : "+v"(u[w]), "+v"(u[w + 1]), "+v"(u[w + 2]), "+v"(u[w + 3]));

    const float scj = sc[j];

    if (j < 16) hq_lds4[j] = make_int4(0, 0, 0, 0);
    float c = 0.f;

    const int step = dir ? -1 : 1;
    int t = dir ? (T_STEPS - 1) : 0;
    float zx = Zx[(size_t)t * G4 + j];
    float* outp = outbase + 2048 + dir * NH;
    __syncthreads();

    for (int s = 0; s < T_STEPS; ++s) {
        const int tn = (s + 1 < T_STEPS) ? t + step : t;
        // prefetch next step's zx row (latency hidden under this step's compute)
        const float nzx = Zx[(size_t)tn * G4 + j];

        int acc = 0;
#pragma unroll
        for (int w4 = 0; w4 < 16; ++w4) {
            const int4 hw = hq_lds4[w4];  // broadcast read
            acc = dot4(u[4 * w4 + 0], hw.x, acc);
            acc = dot4(u[4 * w4 + 1], hw.y, acc);
            acc = dot4(u[4 * w4 + 2], hw.z, acc);
            acc = dot4(u[4 * w4 + 3], hw.w, acc);
        }
        z_lds[j] = zx + (float)acc * scj;
        __syncthreads();

        if (j < NH) {
            float zi = z_lds[j];
            float zf = z_lds[j + NH];
            float zg = z_lds[j + 2 * NH];
            float zo = z_lds[j + 3 * NH];
            c = sigf(zf) * c + sigf(zi) * sigf(zg);
            float h = sigf(zo) * sigf(c);
            outp[(size_t)t * OUTW + j] = h;
            int q = __float2int_rn(h * 127.f);
            q = max(0, min(127, q));
            ((uint8_t*)hq_lds4)[j] = (uint8_t)q;
        }
        __syncthreads();

        zx = nzx;
        t = tn;
    }
}

// ---------------------------------------------------------------- launch
extern "C" void kernel_launch(void* const* d_in, const int* in_sizes, int n_in,
                              void* d_out, int out_size, void* d_ws, size_t ws_size,
                              hipStream_t stream) {
    const float* x   = (const float*)d_in[0];
    const float* W1f = (const float*)d_in[1];
    const float* U1f = (const float*)d_in[2];
    const float* b1f = (const float*)d_in[3];
    const float* W1b = (const float*)d_in[4];
    const float* U1b = (const float*)d_in[5];
    const float* b1b = (const float*)d_in[6];
    const float* W2f = (const float*)d_in[7];
    const float* U2f = (const float*)d_in[8];
    const float* b2f = (const float*)d_in[9];
    const float* W2b = (const float*)d_in[10];
    const float* U2b = (const float*)d_in[11];
    const float* b2b = (const float*)d_in[12];

    float* out  = (float*)d_out;
    float* out1 = out + (size_t)T_STEPS * OUTW;

    // workspace layout
    float* Zxf = (float*)d_ws;
    float* Zxb = Zxf + (size_t)T_STEPS * G4;
    uint32_t* uq = (uint32_t*)(Zxb + (size_t)T_STEPS * G4);  // 4 * 64*1024 words
    float* scq = (float*)(uq + (size_t)4 * 64 * G4);          // 4 * 1024 floats

    // 1) quantize the four U matrices
    quant_u_kernel<<<4, 1024, 0, stream>>>(U1f, U1b, U2f, U2b, uq, scq);

    // 2) copy x into both output slabs
    copy_x_kernel<<<2048, 256, 0, stream>>>((const float4*)x, out);

    dim3 gg(16, 128);
    // 3) layer-1 input projections
    gemm_zx_kernel<<<gg, 256, 0, stream>>>(x, DIN, W1f, b1f, Zxf, DIN);
    gemm_zx_kernel<<<gg, 256, 0, stream>>>(x, DIN, W1b, b1b, Zxb, DIN);

    // 4) layer-1 scans (write M1 into out slab 0, cols 2048..2559)
    lstm_scan_kernel<<<2, 1024, 0, stream>>>(Zxf, Zxb,
                                             uq + (size_t)0 * 64 * G4, uq + (size_t)1 * 64 * G4,
                                             scq + 0 * G4, scq + 1 * G4, out);

    // 5) layer-2 input projections (A = M1, read from out slab 0)
    gemm_zx_kernel<<<gg, 256, 0, stream>>>(out + 2048, OUTW, W2f, b2f, Zxf, 512);
    gemm_zx_kernel<<<gg, 256, 0, stream>>>(out + 2048, OUTW, W2b, b2b, Zxb, 512);

    // 6) layer-2 scans (write M2 into out slab 1)
    lstm_scan_kernel<<<2, 1024, 0, stream>>>(Zxf, Zxb,
                                             uq + (size_t)2 * 64 * G4, uq + (size_t)3 * 64 * G4,
                                             scq + 2 * G4, scq + 3 * G4, out1);
}